// Round 2
// baseline (769.537 us; speedup 1.0000x reference)
//
#include <hip/hip_runtime.h>

#define C 32
#define BSH 7
#define BN 128            // nodes per bucket
#define CAPC 3072         // per-bucket entry capacity (mean 2048, +22 sigma)
#define SRCMASK 0x1FFFF
#define ASTR 33           // padded LDS accumulator row stride (floats): bank=(node+ch)%32

typedef float f32x4 __attribute__((ext_vector_type(4)));

__device__ __forceinline__ unsigned int f2bf(float f) {
    unsigned int u = __float_as_uint(f);
    return (u + 0x7FFFu + ((u >> 16) & 1u)) >> 16;   // RNE to bf16
}
__device__ __forceinline__ float bflo(unsigned int u) { return __uint_as_float(u << 16); }
__device__ __forceinline__ float bfhi(unsigned int u) { return __uint_as_float(u & 0xFFFF0000u); }

// Phase A: bucketize by dst>>7 via LDS hist + per-bucket global reservation.
// 256 blocks so each (block,bucket) reserves a ~8-word contiguous run ->
// 32B write runs, ~2x write amp (round-1 showed CSR-order scatter = 16x amp,
// 107MB HBM writes, 133us). Fused grid-stride x->bf16 conversion.
__global__ __launch_bounds__(1024) void phaseA_cvt(const int* __restrict__ src,
                                                   const int* __restrict__ dst,
                                                   int* __restrict__ cursor,
                                                   int* __restrict__ pk,
                                                   const float* __restrict__ x,
                                                   uint2* __restrict__ xb2,
                                                   int N, int E, int nbuck, int chunk) {
    extern __shared__ int l[];          // lcnt[nbuck] | lcur[nbuck]
    int* lcnt = l;
    int* lcur = l + nbuck;
    int tid = threadIdx.x;
    for (int i = tid; i < nbuck; i += 1024) lcnt[i] = 0;
    __syncthreads();
    int base = blockIdx.x * chunk;
    int end  = min(base + chunk, E);
    for (int e = base + tid; e < end; e += 1024)
        atomicAdd(&lcnt[dst[e] >> BSH], 1);
    __syncthreads();
    for (int i = tid; i < nbuck; i += 1024) {
        int c = lcnt[i];
        lcur[i] = i * CAPC + (c ? atomicAdd(&cursor[i], c) : 0);
    }
    __syncthreads();
    for (int e = base + tid; e < end; e += 1024) {
        int d = dst[e];
        int b = d >> BSH;
        int pos = atomicAdd(&lcur[b], 1);
        pk[pos] = src[e] | ((d & (BN - 1)) << 17);
    }
    int total = N * 8;
    int gid = blockIdx.x * 1024 + tid;
    int gth = gridDim.x * 1024;
    for (int i = gid; i < total; i += gth) {
        f32x4 v = *(const f32x4*)(x + (size_t)i * 4);
        uint2 r;
        r.x = f2bf(v.x) | (f2bf(v.y) << 16);
        r.y = f2bf(v.z) | (f2bf(v.w) << 16);
        xb2[i] = r;
    }
}

// mv1: t1 = deg*x - A@x via direct LDS f32 accumulation (no sort, no CSR).
// Each 8-lane group handles one edge entry: gathers the 64B bf16 x-row of
// src, ds_add_f32's 4 channels per lane into acc[localdst][*].
__global__ __launch_bounds__(1024) void k_mv1_acc(const int* __restrict__ pk,
        const int* __restrict__ cursor, const uint2* __restrict__ xb2,
        uint2* __restrict__ t1b2, int* __restrict__ ideg, int N) {
    __shared__ float acc[BN * ASTR];
    __shared__ int cnt[BN];
    __shared__ int stg[CAPC];
    int b = blockIdx.x;
    int tid = threadIdx.x;
    int n0 = b << BSH;
    int total = min(cursor[b], CAPC);
    for (int i = tid; i < BN * ASTR; i += 1024) acc[i] = 0.f;
    if (tid < BN) cnt[tid] = 0;
    for (int i = tid; i < total; i += 1024)
        stg[i] = __builtin_nontemporal_load(&pk[b * CAPC + i]);
    __syncthreads();
    int lq = tid & 7;
    int grp = tid >> 3;                 // 0..127
    int i = grp;
    for (; i + 128 < total; i += 256) { // 2-deep unroll: both gathers in flight
        int e0 = stg[i];
        int e1 = stg[i + 128];
        uint2 u0 = xb2[(size_t)(e0 & SRCMASK) * 8 + lq];
        uint2 u1 = xb2[(size_t)(e1 & SRCMASK) * 8 + lq];
        float* a0 = &acc[(e0 >> 17) * ASTR + lq * 4];
        float* a1 = &acc[(e1 >> 17) * ASTR + lq * 4];
        atomicAdd(&a0[0], bflo(u0.x));
        atomicAdd(&a0[1], bfhi(u0.x));
        atomicAdd(&a0[2], bflo(u0.y));
        atomicAdd(&a0[3], bfhi(u0.y));
        atomicAdd(&a1[0], bflo(u1.x));
        atomicAdd(&a1[1], bfhi(u1.x));
        atomicAdd(&a1[2], bflo(u1.y));
        atomicAdd(&a1[3], bfhi(u1.y));
        if (lq == 0) { atomicAdd(&cnt[e0 >> 17], 1); atomicAdd(&cnt[e1 >> 17], 1); }
    }
    if (i < total) {
        int e0 = stg[i];
        uint2 u0 = xb2[(size_t)(e0 & SRCMASK) * 8 + lq];
        float* a0 = &acc[(e0 >> 17) * ASTR + lq * 4];
        atomicAdd(&a0[0], bflo(u0.x));
        atomicAdd(&a0[1], bfhi(u0.x));
        atomicAdd(&a0[2], bflo(u0.y));
        atomicAdd(&a0[3], bfhi(u0.y));
        if (lq == 0) atomicAdd(&cnt[e0 >> 17], 1);
    }
    __syncthreads();
    int n = n0 + grp;                   // one (node, lane-quarter) per thread
    if (n < N) {
        int dg = cnt[grp];
        float fdg = (float)dg;
        uint2 xs = xb2[(size_t)n * 8 + lq];
        const float* a = &acc[grp * ASTR + lq * 4];
        uint2 rr;
        rr.x = f2bf(fdg * bflo(xs.x) - a[0]) | (f2bf(fdg * bfhi(xs.x) - a[1]) << 16);
        rr.y = f2bf(fdg * bflo(xs.y) - a[2]) | (f2bf(fdg * bfhi(xs.y) - a[3]) << 16);
        t1b2[(size_t)n * 8 + lq] = rr;  // keep cache-resident for mv2
        if (lq == 0) ideg[n] = dg;
    }
}

// mv2: y = w0*x + w1*t1 + w2*(deg*t1 - A@t1), same accumulate over t1b2.
__global__ __launch_bounds__(1024) void k_mv2_acc(const int* __restrict__ pk,
        const int* __restrict__ cursor, const uint2* __restrict__ xb2,
        const uint2* __restrict__ t1b2, const int* __restrict__ ideg,
        const float* __restrict__ wts, float* __restrict__ y, int N) {
    __shared__ float acc[BN * ASTR];
    __shared__ int stg[CAPC];
    int b = blockIdx.x;
    int tid = threadIdx.x;
    int n0 = b << BSH;
    int total = min(cursor[b], CAPC);
    for (int i = tid; i < BN * ASTR; i += 1024) acc[i] = 0.f;
    for (int i = tid; i < total; i += 1024)
        stg[i] = __builtin_nontemporal_load(&pk[b * CAPC + i]);
    __syncthreads();
    int lq = tid & 7;
    int grp = tid >> 3;
    int i = grp;
    for (; i + 128 < total; i += 256) {
        int e0 = stg[i];
        int e1 = stg[i + 128];
        uint2 u0 = t1b2[(size_t)(e0 & SRCMASK) * 8 + lq];
        uint2 u1 = t1b2[(size_t)(e1 & SRCMASK) * 8 + lq];
        float* a0 = &acc[(e0 >> 17) * ASTR + lq * 4];
        float* a1 = &acc[(e1 >> 17) * ASTR + lq * 4];
        atomicAdd(&a0[0], bflo(u0.x));
        atomicAdd(&a0[1], bfhi(u0.x));
        atomicAdd(&a0[2], bflo(u0.y));
        atomicAdd(&a0[3], bfhi(u0.y));
        atomicAdd(&a1[0], bflo(u1.x));
        atomicAdd(&a1[1], bfhi(u1.x));
        atomicAdd(&a1[2], bflo(u1.y));
        atomicAdd(&a1[3], bfhi(u1.y));
    }
    if (i < total) {
        int e0 = stg[i];
        uint2 u0 = t1b2[(size_t)(e0 & SRCMASK) * 8 + lq];
        float* a0 = &acc[(e0 >> 17) * ASTR + lq * 4];
        atomicAdd(&a0[0], bflo(u0.x));
        atomicAdd(&a0[1], bfhi(u0.x));
        atomicAdd(&a0[2], bflo(u0.y));
        atomicAdd(&a0[3], bfhi(u0.y));
    }
    __syncthreads();
    int n = n0 + grp;
    if (n < N) {
        float w0 = wts[0], w1 = wts[1], w2 = wts[2];
        float fdg = (float)ideg[n];
        uint2 xs = xb2[(size_t)n * 8 + lq];
        uint2 ts = t1b2[(size_t)n * 8 + lq];
        const float* a = &acc[grp * ASTR + lq * 4];
        f32x4 rr;
        rr.x = w0 * bflo(xs.x) + w1 * bflo(ts.x) + w2 * (fdg * bflo(ts.x) - a[0]);
        rr.y = w0 * bfhi(xs.x) + w1 * bfhi(ts.x) + w2 * (fdg * bfhi(ts.x) - a[1]);
        rr.z = w0 * bflo(xs.y) + w1 * bflo(ts.y) + w2 * (fdg * bflo(ts.y) - a[2]);
        rr.w = w0 * bfhi(xs.y) + w1 * bfhi(ts.y) + w2 * (fdg * bfhi(ts.y) - a[3]);
        __builtin_nontemporal_store(rr, (f32x4*)(y + (size_t)n * C + lq * 4));
    }
}

extern "C" void kernel_launch(void* const* d_in, const int* in_sizes, int n_in,
                              void* d_out, int out_size, void* d_ws, size_t ws_size,
                              hipStream_t stream) {
    const float* x    = (const float*)d_in[0];
    const float* wts  = (const float*)d_in[1];
    const int*   esrc = (const int*)d_in[2];
    const int*   edst = (const int*)d_in[3];
    float*       y    = (float*)d_out;

    const int N = in_sizes[0] / C;                 // 100000
    const int E = in_sizes[2];                     // 1600000
    const int nbuck = (N + BN - 1) >> BSH;         // 782
    const int nc = N * C;

    char* p = (char*)d_ws;
    auto align16 = [](size_t s) { return (s + 15) & ~(size_t)15; };
    int* cursor = (int*)p; p += align16((size_t)nbuck * 4);
    int* ideg   = (int*)p; p += align16((size_t)N * 4);
    int* pk     = (int*)p; p += align16((size_t)nbuck * CAPC * 4);
    uint2* xb2  = (uint2*)p; p += align16((size_t)nc * 2);
    uint2* t1b2 = (uint2*)p; p += align16((size_t)nc * 2);
    (void)ws_size;

    hipMemsetAsync(cursor, 0, (size_t)nbuck * 4, stream);

    const int ABLK = 256;                          // chunk/nbuck ~= 8-word runs
    const int chunk = (E + ABLK - 1) / ABLK;
    const size_t lds_a = (size_t)nbuck * 2 * 4;

    phaseA_cvt<<<ABLK, 1024, lds_a, stream>>>(esrc, edst, cursor, pk, x, xb2,
                                              N, E, nbuck, chunk);
    k_mv1_acc<<<nbuck, 1024, 0, stream>>>(pk, cursor, xb2, t1b2, ideg, N);
    k_mv2_acc<<<nbuck, 1024, 0, stream>>>(pk, cursor, xb2, t1b2, ideg, wts, y, N);
}

// Round 4
// 164.127 us; speedup vs baseline: 4.6887x; 4.6887x over previous
//
#include <hip/hip_runtime.h>

#define C 32
#define NT 256
#define BSH 8
#define BNODE 256
#define CAPC 5632          // per-bucket capacity (mean 4096, wide margin)
#define SRCMASK 0x1FFFF

typedef float f32x4 __attribute__((ext_vector_type(4)));

__device__ __forceinline__ unsigned int f2bf(float f) {
    unsigned int u = __float_as_uint(f);
    return (u + 0x7FFFu + ((u >> 16) & 1u)) >> 16;   // RNE to bf16
}
__device__ __forceinline__ float bflo(unsigned int u) { return __uint_as_float(u << 16); }
__device__ __forceinline__ float bfhi(unsigned int u) { return __uint_as_float(u & 0xFFFF0000u); }

// Phase A (verified baseline): bucketize by dst>>8 via LDS hist + per-bucket
// global reservation, fused grid-stride x->bf16 conversion.
__global__ __launch_bounds__(1024) void phaseA_cvt(const int* __restrict__ src,
                                                   const int* __restrict__ dst,
                                                   int* __restrict__ cursor,
                                                   int* __restrict__ pk,
                                                   const float* __restrict__ x,
                                                   uint2* __restrict__ xb2,
                                                   int N, int E, int nbuck, int chunk) {
    extern __shared__ int l[];          // lcnt[nbuck] | lcur[nbuck]
    int* lcnt = l;
    int* lcur = l + nbuck;
    int tid = threadIdx.x;
    for (int i = tid; i < nbuck; i += 1024) lcnt[i] = 0;
    __syncthreads();
    int base = blockIdx.x * chunk;
    int end  = min(base + chunk, E);
    for (int e = base + tid; e < end; e += 1024)
        atomicAdd(&lcnt[dst[e] >> BSH], 1);
    __syncthreads();
    for (int i = tid; i < nbuck; i += 1024) {
        int c = lcnt[i];
        lcur[i] = i * CAPC + (c ? atomicAdd(&cursor[i], c) : 0);
    }
    __syncthreads();
    for (int e = base + tid; e < end; e += 1024) {
        int d = dst[e];
        int b = d >> BSH;
        int pos = atomicAdd(&lcur[b], 1);
        pk[pos] = src[e] | ((d & (BNODE - 1)) << 17);
    }
    int total = N * 8;
    int gid = blockIdx.x * 1024 + tid;
    int gth = gridDim.x * 1024;
    for (int i = gid; i < total; i += gth) {
        f32x4 v = *(const f32x4*)(x + (size_t)i * 4);
        uint2 r;
        r.x = f2bf(v.x) | (f2bf(v.y) << 16);
        r.y = f2bf(v.z) | (f2bf(v.w) << 16);
        xb2[i] = r;
    }
}

// accumulate bf16 rows over LDS indices idx[lo..hi) for lane-quarter lq.
// 8-deep unroll: 8 gather lines in flight per 8-lane group.
__device__ __forceinline__ void accum_lds(const uint2* __restrict__ arr,
                                          const int* idx,
                                          int lo, int hi, int lq,
                                          float& a0, float& a1, float& a2, float& a3) {
#define ACC4(u) { a0 += bflo(u.x); a1 += bfhi(u.x); a2 += bflo(u.y); a3 += bfhi(u.y); }
    int j = lo;
    for (; j + 7 < hi; j += 8) {
        int s0 = idx[j],     s1 = idx[j + 1], s2 = idx[j + 2], s3 = idx[j + 3];
        int s4 = idx[j + 4], s5 = idx[j + 5], s6 = idx[j + 6], s7 = idx[j + 7];
        uint2 u0 = arr[(size_t)s0 * 8 + lq];
        uint2 u1 = arr[(size_t)s1 * 8 + lq];
        uint2 u2 = arr[(size_t)s2 * 8 + lq];
        uint2 u3 = arr[(size_t)s3 * 8 + lq];
        uint2 u4 = arr[(size_t)s4 * 8 + lq];
        uint2 u5 = arr[(size_t)s5 * 8 + lq];
        uint2 u6 = arr[(size_t)s6 * 8 + lq];
        uint2 u7 = arr[(size_t)s7 * 8 + lq];
        ACC4(u0) ACC4(u1) ACC4(u2) ACC4(u3) ACC4(u4) ACC4(u5) ACC4(u6) ACC4(u7)
    }
    for (; j + 3 < hi; j += 4) {
        int s0 = idx[j], s1 = idx[j + 1], s2 = idx[j + 2], s3 = idx[j + 3];
        uint2 u0 = arr[(size_t)s0 * 8 + lq];
        uint2 u1 = arr[(size_t)s1 * 8 + lq];
        uint2 u2 = arr[(size_t)s2 * 8 + lq];
        uint2 u3 = arr[(size_t)s3 * 8 + lq];
        ACC4(u0) ACC4(u1) ACC4(u2) ACC4(u3)
    }
    for (; j < hi; ++j) {
        uint2 u0 = arr[(size_t)idx[j] * 8 + lq];
        ACC4(u0)
    }
#undef ACC4
}

// Phase B fused with matvec1 (verified baseline structure): per-bucket counting
// sort in LDS, write sorted src back to pk + row bounds, then t1 = bf16(deg*x - A@x)
// reading indices straight from LDS.
__global__ __launch_bounds__(1024) void phaseB_mv1(int* __restrict__ pk,
                                                   const int* __restrict__ cursor,
                                                   int* __restrict__ row_start,
                                                   int* __restrict__ ideg,
                                                   const uint2* __restrict__ xb2,
                                                   uint2* __restrict__ t1b2, int N) {
    __shared__ int ent[CAPC];
    __shared__ int sorted[CAPC];
    __shared__ int h[BNODE];
    __shared__ int ss[BNODE];
    __shared__ int cur[BNODE];
    int b = blockIdx.x;
    int tid = threadIdx.x;
    int n0 = b << BSH;
    int base = b * CAPC;
    int cnt = min(cursor[b], CAPC);

    if (tid < BNODE) h[tid] = 0;
    __syncthreads();
    for (int i = tid; i < cnt; i += 1024) {
        int en = __builtin_nontemporal_load(&pk[base + i]);
        ent[i] = en;
        atomicAdd(&h[en >> 17], 1);
    }
    __syncthreads();
    int v = 0;
    if (tid < BNODE) { v = h[tid]; ss[tid] = v; }
    __syncthreads();
    for (int off = 1; off < BNODE; off <<= 1) {
        int u = 0;
        if (tid < BNODE && tid >= off) u = ss[tid - off];
        __syncthreads();
        if (tid < BNODE) ss[tid] += u;
        __syncthreads();
    }
    if (tid < BNODE) {
        int exc = ss[tid] - v;
        int n = n0 + tid;
        if (n < N) { row_start[n] = base + exc; ideg[n] = v; }
        cur[tid] = exc;
    }
    __syncthreads();
    for (int i = tid; i < cnt; i += 1024) {
        int en = ent[i];
        int pos = atomicAdd(&cur[en >> 17], 1);
        int s = en & SRCMASK;
        sorted[pos] = s;
        pk[base + pos] = s;            // gather2_lds stages this
    }
    __syncthreads();

    // ---- matvec1 from LDS indices: 256 nodes x 8 lane-quarters ----
    for (int it = tid; it < BNODE * 8; it += 1024) {
        int r = it >> 3;
        int lq = it & 7;
        int n = n0 + r;
        if (n >= N) continue;
        int hi = ss[r];
        int lo = hi - h[r];
        float a0 = 0.f, a1 = 0.f, a2 = 0.f, a3 = 0.f;
        accum_lds(xb2, sorted, lo, hi, lq, a0, a1, a2, a3);
        uint2 xs = xb2[(size_t)n * 8 + lq];
        float fdg = (float)h[r];
        uint2 rr;
        rr.x = f2bf(fdg * bflo(xs.x) - a0) | (f2bf(fdg * bfhi(xs.x) - a1) << 16);
        rr.y = f2bf(fdg * bflo(xs.y) - a2) | (f2bf(fdg * bfhi(xs.y) - a3) << 16);
        t1b2[(size_t)n * 8 + lq] = rr;  // regular store: keep L2/L3-resident for gather2
    }
}

// gather2 with LDS-staged indices: stage this bucket's sorted pk segment into
// LDS (coalesced burst), then y = w0*x + w1*t1 + w2*(deg*t1 - A@t1) with the
// segment walk hitting LDS instead of per-thread global pointer-chase.
__global__ __launch_bounds__(1024) void gather2_lds(const uint2* __restrict__ xb2,
        const uint2* __restrict__ t1b2, const int* __restrict__ pk,
        const int* __restrict__ cursor, const int* __restrict__ row_start,
        const int* __restrict__ ideg, const float* __restrict__ wts,
        float* __restrict__ y, int N) {
    __shared__ int stg[CAPC];
    int b = blockIdx.x;
    int tid = threadIdx.x;
    int n0 = b << BSH;
    int base = b * CAPC;
    int cnt = min(cursor[b], CAPC);
    for (int i = tid; i < cnt; i += 1024)
        stg[i] = __builtin_nontemporal_load(&pk[base + i]);
    __syncthreads();
    float w0 = wts[0], w1 = wts[1], w2 = wts[2];
    for (int it = tid; it < BNODE * 8; it += 1024) {
        int r = it >> 3;
        int lq = it & 7;
        int n = n0 + r;
        if (n >= N) continue;
        int dg = ideg[n];
        int lo = row_start[n] - base;      // local offset in stg
        int hi = lo + dg;
        float a0 = 0.f, a1 = 0.f, a2 = 0.f, a3 = 0.f;
        accum_lds(t1b2, stg, lo, hi, lq, a0, a1, a2, a3);
        uint2 xs = xb2[(size_t)n * 8 + lq];
        uint2 ts = t1b2[(size_t)n * 8 + lq];
        float fdg = (float)dg;
        f32x4 rq;
        rq.x = w0 * bflo(xs.x) + w1 * bflo(ts.x) + w2 * (fdg * bflo(ts.x) - a0);
        rq.y = w0 * bfhi(xs.x) + w1 * bfhi(ts.x) + w2 * (fdg * bfhi(ts.x) - a1);
        rq.z = w0 * bflo(xs.y) + w1 * bflo(ts.y) + w2 * (fdg * bflo(ts.y) - a2);
        rq.w = w0 * bfhi(xs.y) + w1 * bfhi(ts.y) + w2 * (fdg * bfhi(ts.y) - a3);
        __builtin_nontemporal_store(rq, (f32x4*)(y + (size_t)n * C + lq * 4));
    }
}

extern "C" void kernel_launch(void* const* d_in, const int* in_sizes, int n_in,
                              void* d_out, int out_size, void* d_ws, size_t ws_size,
                              hipStream_t stream) {
    const float* x    = (const float*)d_in[0];
    const float* wts  = (const float*)d_in[1];
    const int*   esrc = (const int*)d_in[2];
    const int*   edst = (const int*)d_in[3];
    float*       y    = (float*)d_out;

    const int N = in_sizes[0] / C;                 // 100000
    const int E = in_sizes[2];                     // 1600000
    const int nbuck = (N + BNODE - 1) >> BSH;      // 391
    const int nc = N * C;

    char* p = (char*)d_ws;
    auto align16 = [](size_t s) { return (s + 15) & ~(size_t)15; };
    int* cursor    = (int*)p; p += align16((size_t)nbuck * 4);
    int* row_start = (int*)p; p += align16((size_t)N * 4);
    int* ideg      = (int*)p; p += align16((size_t)N * 4);
    int* pk        = (int*)p; p += align16((size_t)nbuck * CAPC * 4);
    uint2* xb2     = (uint2*)p; p += align16((size_t)nc * 2);
    uint2* t1b2    = (uint2*)p; p += align16((size_t)nc * 2);
    (void)ws_size;

    hipMemsetAsync(cursor, 0, (size_t)nbuck * 4, stream);

    const int ABLK = 512;
    const int chunk = (E + ABLK - 1) / ABLK;
    const size_t lds_a = (size_t)nbuck * 2 * 4;

    phaseA_cvt<<<ABLK, 1024, lds_a, stream>>>(esrc, edst, cursor, pk, x, xb2,
                                              N, E, nbuck, chunk);
    phaseB_mv1<<<nbuck, 1024, 0, stream>>>(pk, cursor, row_start, ideg,
                                           xb2, t1b2, N);
    gather2_lds<<<nbuck, 1024, 0, stream>>>(xb2, t1b2, pk, cursor, row_start,
                                            ideg, wts, y, N);
}

// Round 6
// 159.925 us; speedup vs baseline: 4.8119x; 1.0263x over previous
//
#include <hip/hip_runtime.h>

#define C 32
#define BSH 8
#define BNODE 256
#define CAPC 5632          // per-bucket capacity (mean 4096, wide margin)
#define SRCMASK 0x1FFFF

typedef float f32x4 __attribute__((ext_vector_type(4)));
typedef float f32x2 __attribute__((ext_vector_type(2)));

__device__ __forceinline__ unsigned int f2bf(float f) {
    unsigned int u = __float_as_uint(f);
    return (u + 0x7FFFu + ((u >> 16) & 1u)) >> 16;   // RNE to bf16
}
__device__ __forceinline__ float bflo(unsigned int u) { return __uint_as_float(u << 16); }
__device__ __forceinline__ float bfhi(unsigned int u) { return __uint_as_float(u & 0xFFFF0000u); }

// Phase A (verified): bucketize by dst>>8 via LDS hist + per-bucket global
// reservation. x -> bf16 conversion writes TWO half-tables (channels
// 0-15 | 16-31), each 3.2MB with 32B rows, so each matvec pass's gather
// working set fits a single XCD's 4MB L2 (round-2 PMC: 6.4MB table -> 48.8MB
// L2-miss FETCH on the gather kernel = L2 thrash; this is the fix).
__global__ __launch_bounds__(1024) void phaseA_cvt(const int* __restrict__ src,
                                                   const int* __restrict__ dst,
                                                   int* __restrict__ cursor,
                                                   int* __restrict__ pk,
                                                   const float* __restrict__ x,
                                                   unsigned int* __restrict__ xbh,
                                                   int N, int E, int nbuck, int chunk) {
    extern __shared__ int l[];          // lcnt[nbuck] | lcur[nbuck]
    int* lcnt = l;
    int* lcur = l + nbuck;
    int tid = threadIdx.x;
    for (int i = tid; i < nbuck; i += 1024) lcnt[i] = 0;
    __syncthreads();
    int base = blockIdx.x * chunk;
    int end  = min(base + chunk, E);
    for (int e = base + tid; e < end; e += 1024)
        atomicAdd(&lcnt[dst[e] >> BSH], 1);
    __syncthreads();
    for (int i = tid; i < nbuck; i += 1024) {
        int c = lcnt[i];
        lcur[i] = i * CAPC + (c ? atomicAdd(&cursor[i], c) : 0);
    }
    __syncthreads();
    for (int e = base + tid; e < end; e += 1024) {
        int d = dst[e];
        int b = d >> BSH;
        int pos = atomicAdd(&lcur[b], 1);
        pk[pos] = src[e] | ((d & (BNODE - 1)) << 17);
    }
    // conversion: chunk i covers channels 4q..4q+3 of node i>>3.
    // half = q>>2, uint2 slot (q&3) of row in half-table.
    int total = N * 8;
    int gid = blockIdx.x * 1024 + tid;
    int gth = gridDim.x * 1024;
    for (int i = gid; i < total; i += gth) {
        f32x4 v = *(const f32x4*)(x + (size_t)i * 4);
        uint2 r;
        r.x = f2bf(v.x) | (f2bf(v.y) << 16);
        r.y = f2bf(v.z) | (f2bf(v.w) << 16);
        int node = i >> 3;
        int q = i & 7;
        int half = q >> 2;
        ((uint2*)xbh)[((size_t)half * N + node) * 4 + (q & 3)] = r;
    }
}

// accumulate one half-table (2 channels per lane) over LDS indices idx[lo..hi).
// 8-deep unroll: 8 independent 32B-line gathers in flight per 8-lane group.
__device__ __forceinline__ void accum_h(const unsigned int* __restrict__ tab,
                                        const int* idx, int lo, int hi, int lq,
                                        float& a0, float& a1) {
#define ACC2(u) { a0 += bflo(u); a1 += bfhi(u); }
    int j = lo;
    for (; j + 7 < hi; j += 8) {
        int s0 = idx[j],     s1 = idx[j + 1], s2 = idx[j + 2], s3 = idx[j + 3];
        int s4 = idx[j + 4], s5 = idx[j + 5], s6 = idx[j + 6], s7 = idx[j + 7];
        unsigned int u0 = tab[(size_t)s0 * 8 + lq];
        unsigned int u1 = tab[(size_t)s1 * 8 + lq];
        unsigned int u2 = tab[(size_t)s2 * 8 + lq];
        unsigned int u3 = tab[(size_t)s3 * 8 + lq];
        unsigned int u4 = tab[(size_t)s4 * 8 + lq];
        unsigned int u5 = tab[(size_t)s5 * 8 + lq];
        unsigned int u6 = tab[(size_t)s6 * 8 + lq];
        unsigned int u7 = tab[(size_t)s7 * 8 + lq];
        ACC2(u0) ACC2(u1) ACC2(u2) ACC2(u3) ACC2(u4) ACC2(u5) ACC2(u6) ACC2(u7)
    }
    for (; j + 3 < hi; j += 4) {
        int s0 = idx[j], s1 = idx[j + 1], s2 = idx[j + 2], s3 = idx[j + 3];
        unsigned int u0 = tab[(size_t)s0 * 8 + lq];
        unsigned int u1 = tab[(size_t)s1 * 8 + lq];
        unsigned int u2 = tab[(size_t)s2 * 8 + lq];
        unsigned int u3 = tab[(size_t)s3 * 8 + lq];
        ACC2(u0) ACC2(u1) ACC2(u2) ACC2(u3)
    }
    for (; j < hi; ++j) {
        unsigned int u0 = tab[(size_t)idx[j] * 8 + lq];
        ACC2(u0)
    }
#undef ACC2
}

// Phase B + matvec1: per-bucket counting sort in LDS, coalesced pk write-back,
// then t1 = bf16(deg*x - A@x) in two channel-half passes (3.2MB working set
// each) reading indices straight from LDS.
__global__ __launch_bounds__(1024) void phaseB_mv1(int* __restrict__ pk,
                                                   const int* __restrict__ cursor,
                                                   int* __restrict__ row_start,
                                                   int* __restrict__ ideg,
                                                   const unsigned int* __restrict__ xbh,
                                                   unsigned int* __restrict__ t1h, int N) {
    __shared__ int ent[CAPC];
    __shared__ int sorted[CAPC];
    __shared__ int h[BNODE];
    __shared__ int ss[BNODE];
    __shared__ int cur[BNODE];
    int b = blockIdx.x;
    int tid = threadIdx.x;
    int n0 = b << BSH;
    int base = b * CAPC;
    int cnt = min(cursor[b], CAPC);

    if (tid < BNODE) h[tid] = 0;
    __syncthreads();
    for (int i = tid; i < cnt; i += 1024) {
        int en = __builtin_nontemporal_load(&pk[base + i]);
        ent[i] = en;
        atomicAdd(&h[en >> 17], 1);
    }
    __syncthreads();
    int v = 0;
    if (tid < BNODE) { v = h[tid]; ss[tid] = v; }
    __syncthreads();
    for (int off = 1; off < BNODE; off <<= 1) {
        int u = 0;
        if (tid < BNODE && tid >= off) u = ss[tid - off];
        __syncthreads();
        if (tid < BNODE) ss[tid] += u;
        __syncthreads();
    }
    if (tid < BNODE) {
        int exc = ss[tid] - v;
        int n = n0 + tid;
        if (n < N) { row_start[n] = base + exc; ideg[n] = v; }
        cur[tid] = exc;
    }
    __syncthreads();
    for (int i = tid; i < cnt; i += 1024) {
        int en = ent[i];
        int pos = atomicAdd(&cur[en >> 17], 1);
        sorted[pos] = en & SRCMASK;
    }
    __syncthreads();
    for (int i = tid; i < cnt; i += 1024)          // coalesced write-back
        pk[base + i] = sorted[i];

    // ---- matvec1, two channel-half passes ----
    for (int hf = 0; hf < 2; ++hf) {
        const unsigned int* tab = xbh + (size_t)hf * N * 8;
        unsigned int* ttab = t1h + (size_t)hf * N * 8;
        for (int it = tid; it < BNODE * 8; it += 1024) {
            int r = it >> 3;
            int lq = it & 7;
            int n = n0 + r;
            if (n >= N) continue;
            int hi = ss[r];
            int lo = hi - h[r];
            float a0 = 0.f, a1 = 0.f;
            accum_h(tab, sorted, lo, hi, lq, a0, a1);
            unsigned int xs = tab[(size_t)n * 8 + lq];
            float fdg = (float)h[r];
            unsigned int rr = f2bf(fdg * bflo(xs) - a0)
                            | (f2bf(fdg * bfhi(xs) - a1) << 16);
            ttab[(size_t)n * 8 + lq] = rr;   // regular store: stay L2-resident
        }
    }
}

// gather2: stage sorted pk into LDS (coalesced), then
// y = w0*x + w1*t1 + w2*(deg*t1 - A@t1) in two channel-half passes.
__global__ __launch_bounds__(1024) void gather2_lds(const unsigned int* __restrict__ xbh,
        const unsigned int* __restrict__ t1h, const int* __restrict__ pk,
        const int* __restrict__ cursor, const int* __restrict__ row_start,
        const int* __restrict__ ideg, const float* __restrict__ wts,
        float* __restrict__ y, int N) {
    __shared__ int stg[CAPC];
    int b = blockIdx.x;
    int tid = threadIdx.x;
    int n0 = b << BSH;
    int base = b * CAPC;
    int cnt = min(cursor[b], CAPC);
    for (int i = tid; i < cnt; i += 1024)
        stg[i] = __builtin_nontemporal_load(&pk[base + i]);
    __syncthreads();
    float w0 = wts[0], w1 = wts[1], w2 = wts[2];
    for (int hf = 0; hf < 2; ++hf) {
        const unsigned int* xtab = xbh + (size_t)hf * N * 8;
        const unsigned int* ttab = t1h + (size_t)hf * N * 8;
        for (int it = tid; it < BNODE * 8; it += 1024) {
            int r = it >> 3;
            int lq = it & 7;
            int n = n0 + r;
            if (n >= N) continue;
            int dg = ideg[n];
            int lo = row_start[n] - base;      // local offset in stg
            int hi = lo + dg;
            float a0 = 0.f, a1 = 0.f;
            accum_h(ttab, stg, lo, hi, lq, a0, a1);
            unsigned int xs = xtab[(size_t)n * 8 + lq];
            unsigned int ts = ttab[(size_t)n * 8 + lq];
            float fdg = (float)dg;
            f32x2 yv;
            yv.x = w0 * bflo(xs) + w1 * bflo(ts) + w2 * (fdg * bflo(ts) - a0);
            yv.y = w0 * bfhi(xs) + w1 * bfhi(ts) + w2 * (fdg * bfhi(ts) - a1);
            // channels (hf*16 + 2*lq, +1): 8 lanes -> 64B contiguous
            __builtin_nontemporal_store(yv,
                (f32x2*)(y + (size_t)n * C + hf * 16 + lq * 2));
        }
    }
}

extern "C" void kernel_launch(void* const* d_in, const int* in_sizes, int n_in,
                              void* d_out, int out_size, void* d_ws, size_t ws_size,
                              hipStream_t stream) {
    const float* x    = (const float*)d_in[0];
    const float* wts  = (const float*)d_in[1];
    const int*   esrc = (const int*)d_in[2];
    const int*   edst = (const int*)d_in[3];
    float*       y    = (float*)d_out;

    const int N = in_sizes[0] / C;                 // 100000
    const int E = in_sizes[2];                     // 1600000
    const int nbuck = (N + BNODE - 1) >> BSH;      // 391
    const int nc = N * C;

    char* p = (char*)d_ws;
    auto align16 = [](size_t s) { return (s + 15) & ~(size_t)15; };
    int* cursor    = (int*)p; p += align16((size_t)nbuck * 4);
    int* row_start = (int*)p; p += align16((size_t)N * 4);
    int* ideg      = (int*)p; p += align16((size_t)N * 4);
    int* pk        = (int*)p; p += align16((size_t)nbuck * CAPC * 4);
    unsigned int* xbh = (unsigned int*)p; p += align16((size_t)nc * 2);  // 2 half-tables
    unsigned int* t1h = (unsigned int*)p; p += align16((size_t)nc * 2);
    (void)ws_size;

    (void)hipMemsetAsync(cursor, 0, (size_t)nbuck * 4, stream);

    const int ABLK = 512;
    const int chunk = (E + ABLK - 1) / ABLK;
    const size_t lds_a = (size_t)nbuck * 2 * 4;

    phaseA_cvt<<<ABLK, 1024, lds_a, stream>>>(esrc, edst, cursor, pk, x, xbh,
                                              N, E, nbuck, chunk);
    phaseB_mv1<<<nbuck, 1024, 0, stream>>>(pk, cursor, row_start, ideg,
                                           xbh, t1h, N);
    gather2_lds<<<nbuck, 1024, 0, stream>>>(xbh, t1h, pk, cursor, row_start,
                                            ideg, wts, y, N);
}